// Round 12
// baseline (412.594 us; speedup 1.0000x reference)
//
#include <hip/hip_runtime.h>

// EdgeEmbedding: out[i,:] = ete[data[i],:] + segsum(attr_table[flat_attr_ids], attr_seg_ids)[data[i],:]
// N=1e6, D=256, NUM_TYPES=1000, TOTAL_ATTRS=50k, ATTR_NUM=200k. f32 in/out, idx int32.
// R12: build via LDS-accumulate (each list entry read ONCE per D-chunk; no per-type rescans).
// Gather + finalize byte-identical to R10. Fallback: R9 scan-build (SL=4).

#define EE_D4     64         // float4s per output row
#define EE_NT     1000
#define EE_K      4          // types per scan-build block (fallback path)
#define EE_NSL    8          // list slices for LDS build
#define EE_NCH    16         // D-chunks of 16 floats (16*16 = 256)

typedef float        fvec4 __attribute__((ext_vector_type(4)));
typedef unsigned int uvec2 __attribute__((ext_vector_type(2)));

__device__ __forceinline__ unsigned int ee_pack_bf16(float a, float b) {
    unsigned int ua = __builtin_bit_cast(unsigned int, a);
    unsigned int ub = __builtin_bit_cast(unsigned int, b);
    ua = (ua + 0x7FFFu + ((ua >> 16) & 1u)) >> 16;   // RNE
    ub = (ub + 0x7FFFu + ((ub >> 16) & 1u)) >> 16;
    return ua | (ub << 16);
}

// ---------- R12 build: LDS per-type accumulation ----------
// block (c, s): D-chunk c (floats c*16..c*16+15), list slice s.
// lds[t][sub] accumulates; each entry read once; 16 lanes per entry.
__global__ __launch_bounds__(256) void ee_build_lds(
        const float* __restrict__ attr,
        const int* __restrict__ ids,
        const int* __restrict__ segs,
        float* __restrict__ part, int na) {       // part: f32 [EE_NSL][1000][256]
    const int c     = blockIdx.x;                 // D-chunk
    const int slice = blockIdx.y;
    const int tid   = threadIdx.x;
    const int sub   = tid & 15;                   // column within chunk
    const int slot  = tid >> 4;                   // 16 entry slots

    __shared__ float lds[EE_NT * 16];             // 64,000 B
    for (int i = tid; i < EE_NT * 16; i += 256) lds[i] = 0.f;
    __syncthreads();

    const int chunk = (na + EE_NSL - 1) / EE_NSL;
    const int s0 = slice * chunk;
    const int s1 = (s0 + chunk < na) ? s0 + chunk : na;

    for (int e = s0 + slot; e < s1; e += 16) {
        int t  = segs[e];                         // broadcast within 16-lane group
        int id = ids[e];
        float v = attr[(size_t)id * 256 + c * 16 + sub];   // 64B coalesced per group
        atomicAdd(&lds[t * 16 + sub], v);         // rare conflicts (random types)
    }
    __syncthreads();

    for (int i = tid; i < EE_NT * 16; i += 256) {
        int t = i >> 4, s2 = i & 15;
        part[((size_t)slice * EE_NT + t) * 256 + c * 16 + s2] = lds[i];
    }
}

// ---------- fallback scan-build (R9-proven, needs only 4.5 MB ws) ----------
template <int SL>
__global__ __launch_bounds__(256) void ee_build_part(
        const fvec4* __restrict__ attr,
        const int* __restrict__ ids,
        const int* __restrict__ segs,
        fvec4* __restrict__ part, int na) {
    const int t0    = blockIdx.x * EE_K;
    const int slice = blockIdx.y;
    const int tid   = threadIdx.x;
    const int wave  = tid >> 6;
    const int lane  = tid & 63;

    const int chunk = (na + SL - 1) / SL;
    const int s0 = slice * chunk;
    const int s1 = (s0 + chunk < na) ? s0 + chunk : na;

    fvec4 acc[EE_K];
    #pragma unroll
    for (int k = 0; k < EE_K; ++k) acc[k] = (fvec4)0.f;

    for (int base = s0 + wave * 64; base < s1; base += 256) {
        int a = base + lane;
        int s = -1, id = 0;
        if (a < s1) { s = segs[a]; id = ids[a]; }
        #pragma unroll
        for (int k = 0; k < EE_K; ++k) {
            unsigned long long m = __ballot(s == t0 + k);
            while (m) {
                int j = __ffsll((long long)m) - 1;
                m &= m - 1;
                int aid = __shfl(id, j);
                acc[k] += attr[(size_t)aid * EE_D4 + lane];
            }
        }
    }

    __shared__ fvec4 red[EE_K][4][64];
    #pragma unroll
    for (int k = 0; k < EE_K; ++k) red[k][wave][lane] = acc[k];
    __syncthreads();
    if (wave < EE_K) {
        int k = wave;
        fvec4 r = red[k][0][lane];
        #pragma unroll
        for (int w = 1; w < 4; ++w) r += red[k][w][lane];
        part[((size_t)slice * EE_NT + (t0 + k)) * EE_D4 + lane] = r;
    }
}

// Finalize: comb[t] = pack_bf16( sum_s part[s][t] + ete[t] ).
template <int SL>
__global__ __launch_bounds__(256) void ee_finalize(
        const fvec4* __restrict__ part,
        const fvec4* __restrict__ ete,
        uvec2* __restrict__ comb) {
    const int t    = blockIdx.x * EE_K + (threadIdx.x >> 6);
    const int lane = threadIdx.x & 63;
    fvec4 r = ete[(size_t)t * EE_D4 + lane];
    #pragma unroll
    for (int s = 0; s < SL; ++s)
        r += part[((size_t)s * EE_NT + t) * EE_D4 + lane];
    uvec2 p;
    p.x = ee_pack_bf16(r.x, r.y);
    p.y = ee_pack_bf16(r.z, r.w);
    comb[(size_t)t * EE_D4 + lane] = p;
}

__device__ __forceinline__ fvec4 ee_unpack(uvec2 q) {
    fvec4 v;
    v.x = __builtin_bit_cast(float, q.x << 16);
    v.y = __builtin_bit_cast(float, q.x & 0xFFFF0000u);
    v.z = __builtin_bit_cast(float, q.y << 16);
    v.w = __builtin_bit_cast(float, q.y & 0xFFFF0000u);
    return v;
}

// Phase B: out[r][:] = unpack(comb[data[r]][:]). (byte-identical, ~184 us measured)
__global__ __launch_bounds__(256) void ee_gather_out(
        const int* __restrict__ data,
        const uvec2* __restrict__ comb,
        fvec4* __restrict__ out, int n) {
    const int gid  = blockIdx.x * blockDim.x + threadIdx.x;
    const int wave = gid >> 6;
    const int lane = gid & 63;
    const int nw   = (gridDim.x * blockDim.x) >> 6;

    for (int base = wave * 64; base < n; base += nw * 64) {
        int r = base + lane;
        int idx = (r < n) ? __builtin_nontemporal_load(&data[r]) : 0;
        int lim = n - base;
        if (lim >= 64) {
            #pragma unroll                               // j compile-time -> v_readlane
            for (int j = 0; j < 64; ++j) {
                int t = __builtin_amdgcn_readlane(idx, j);
                uvec2 q = comb[(size_t)t * EE_D4 + lane];
                __builtin_nontemporal_store(ee_unpack(q), &out[(size_t)(base + j) * EE_D4 + lane]);
            }
        } else {
            for (int j = 0; j < lim; ++j) {
                int t = __shfl(idx, j);
                uvec2 q = comb[(size_t)t * EE_D4 + lane];
                __builtin_nontemporal_store(ee_unpack(q), &out[(size_t)(base + j) * EE_D4 + lane]);
            }
        }
    }
}

extern "C" void kernel_launch(void* const* d_in, const int* in_sizes, int n_in,
                              void* d_out, int out_size, void* d_ws, size_t ws_size,
                              hipStream_t stream) {
    const int*   data          = (const int*)d_in[0];
    const float* attr_table    = (const float*)d_in[1];
    const float* ete           = (const float*)d_in[2];
    const int*   flat_attr_ids = (const int*)d_in[3];
    const int*   attr_seg_ids  = (const int*)d_in[4];
    int N  = in_sizes[0];   // 1,000,000 edges
    int TA = in_sizes[3];   // 50,000 ragged attrs

    // ws layout: comb bf16 (512 KB) | part f32 [SL][1000][256] (SL MB)
    char*  ws   = (char*)d_ws;
    uvec2* comb = (uvec2*)ws;
    fvec4* part = (fvec4*)(ws + (512 << 10));
    const size_t partBytes = (size_t)EE_NT * EE_D4 * sizeof(fvec4);   // 1 MB per slice

    if (ws_size >= (512 << 10) + EE_NSL * partBytes) {     // 8.5 MB (proven available in R10)
        ee_build_lds<<<dim3(EE_NCH, EE_NSL), 256, 0, stream>>>(
            attr_table, flat_attr_ids, attr_seg_ids, (float*)part, TA);
        ee_finalize<EE_NSL><<<EE_NT / EE_K, 256, 0, stream>>>(part, (const fvec4*)ete, comb);
    } else {                                               // R9-proven fallback, 4.5 MB
        ee_build_part<4><<<dim3(EE_NT / EE_K, 4), 256, 0, stream>>>(
            (const fvec4*)attr_table, flat_attr_ids, attr_seg_ids, part, TA);
        ee_finalize<4><<<EE_NT / EE_K, 256, 0, stream>>>(part, (const fvec4*)ete, comb);
    }

    ee_gather_out<<<2048, 256, 0, stream>>>(
        data, comb, (fvec4*)d_out, N);
}

// Round 13
// 205.661 us; speedup vs baseline: 2.0062x; 2.0062x over previous
//
#include <hip/hip_runtime.h>

// EdgeEmbedding: out[i,:] = ete[data[i],:] + segsum(attr_table[flat_attr_ids], attr_seg_ids)[data[i],:]
// N=1e6, D=256, NUM_TYPES=1000, TOTAL_ATTRS=50k, ATTR_NUM=200k. f32 in/out, idx int32.
// R13: build = R10's proven K=4/SL=8 scan (~25us). Gather restructured as a
// batched load/store software pipeline (16-row batches, static reg indexing)
// to decouple comb L2 loads from NT stores in the vmcnt queue.

#define EE_D4     64         // float4s per output row
#define EE_NT     1000
#define EE_K      4          // types per build block

typedef float        fvec4 __attribute__((ext_vector_type(4)));
typedef unsigned int uvec2 __attribute__((ext_vector_type(2)));

__device__ __forceinline__ unsigned int ee_pack_bf16(float a, float b) {
    unsigned int ua = __builtin_bit_cast(unsigned int, a);
    unsigned int ub = __builtin_bit_cast(unsigned int, b);
    ua = (ua + 0x7FFFu + ((ua >> 16) & 1u)) >> 16;   // RNE
    ub = (ub + 0x7FFFu + ((ub >> 16) & 1u)) >> 16;
    return ua | (ub << 16);
}

// Phase A: slice-partial scan (R10-proven). block (g, s): types 4g..4g+3, slice s.
template <int SL>
__global__ __launch_bounds__(256) void ee_build_part(
        const fvec4* __restrict__ attr,
        const int* __restrict__ ids,
        const int* __restrict__ segs,
        fvec4* __restrict__ part, int na) {
    const int t0    = blockIdx.x * EE_K;
    const int slice = blockIdx.y;
    const int tid   = threadIdx.x;
    const int wave  = tid >> 6;
    const int lane  = tid & 63;

    const int chunk = (na + SL - 1) / SL;
    const int s0 = slice * chunk;
    const int s1 = (s0 + chunk < na) ? s0 + chunk : na;

    fvec4 acc[EE_K];
    #pragma unroll
    for (int k = 0; k < EE_K; ++k) acc[k] = (fvec4)0.f;

    for (int base = s0 + wave * 64; base < s1; base += 256) {
        int a = base + lane;
        int s = -1, id = 0;
        if (a < s1) { s = segs[a]; id = ids[a]; }        // coalesced 256B loads
        #pragma unroll
        for (int k = 0; k < EE_K; ++k) {
            unsigned long long m = __ballot(s == t0 + k);
            while (m) {
                int j = __ffsll((long long)m) - 1;
                m &= m - 1;
                int aid = __shfl(id, j);
                acc[k] += attr[(size_t)aid * EE_D4 + lane];  // 1KB coalesced row
            }
        }
    }

    __shared__ fvec4 red[EE_K][4][64];
    #pragma unroll
    for (int k = 0; k < EE_K; ++k) red[k][wave][lane] = acc[k];
    __syncthreads();
    if (wave < EE_K) {
        int k = wave;
        fvec4 r = red[k][0][lane];
        #pragma unroll
        for (int w = 1; w < 4; ++w) r += red[k][w][lane];
        part[((size_t)slice * EE_NT + (t0 + k)) * EE_D4 + lane] = r;
    }
}

// Finalize: comb[t] = pack_bf16( sum_s part[s][t] + ete[t] ).
template <int SL>
__global__ __launch_bounds__(256) void ee_finalize(
        const fvec4* __restrict__ part,
        const fvec4* __restrict__ ete,
        uvec2* __restrict__ comb) {
    const int t    = blockIdx.x * EE_K + (threadIdx.x >> 6);
    const int lane = threadIdx.x & 63;
    fvec4 r = ete[(size_t)t * EE_D4 + lane];
    #pragma unroll
    for (int s = 0; s < SL; ++s)
        r += part[((size_t)s * EE_NT + t) * EE_D4 + lane];
    uvec2 p;
    p.x = ee_pack_bf16(r.x, r.y);
    p.y = ee_pack_bf16(r.z, r.w);
    comb[(size_t)t * EE_D4 + lane] = p;
}

__device__ __forceinline__ fvec4 ee_unpack(uvec2 q) {
    fvec4 v;
    v.x = __builtin_bit_cast(float, q.x << 16);
    v.y = __builtin_bit_cast(float, q.x & 0xFFFF0000u);
    v.z = __builtin_bit_cast(float, q.y << 16);
    v.w = __builtin_bit_cast(float, q.y & 0xFFFF0000u);
    return v;
}

// Phase B: out[r][:] = unpack(comb[data[r]][:]).
// R13: 16-row batched pipeline — prefetch batch b+1 loads before storing batch b.
// All register indices compile-time (named qa/qb arrays, full unroll).
__global__ __launch_bounds__(256) void ee_gather_out(
        const int* __restrict__ data,
        const uvec2* __restrict__ comb,
        fvec4* __restrict__ out, int n) {
    const int gid  = blockIdx.x * blockDim.x + threadIdx.x;
    const int wave = gid >> 6;
    const int lane = gid & 63;
    const int nw   = (gridDim.x * blockDim.x) >> 6;

    for (int base = wave * 64; base < n; base += nw * 64) {
        int r = base + lane;
        int idx = (r < n) ? __builtin_nontemporal_load(&data[r]) : 0;
        int lim = n - base;
        if (lim >= 64) {
            uvec2 qa[16], qb[16];
            // prefetch batch 0 -> qa
            #pragma unroll
            for (int j = 0; j < 16; ++j)
                qa[j] = comb[(size_t)__builtin_amdgcn_readlane(idx, j) * EE_D4 + lane];
            // b=0: load batch1 -> qb, store qa (rows 0..15)
            #pragma unroll
            for (int j = 0; j < 16; ++j)
                qb[j] = comb[(size_t)__builtin_amdgcn_readlane(idx, 16 + j) * EE_D4 + lane];
            #pragma unroll
            for (int j = 0; j < 16; ++j)
                __builtin_nontemporal_store(ee_unpack(qa[j]), &out[(size_t)(base + j) * EE_D4 + lane]);
            // b=1: load batch2 -> qa, store qb (rows 16..31)
            #pragma unroll
            for (int j = 0; j < 16; ++j)
                qa[j] = comb[(size_t)__builtin_amdgcn_readlane(idx, 32 + j) * EE_D4 + lane];
            #pragma unroll
            for (int j = 0; j < 16; ++j)
                __builtin_nontemporal_store(ee_unpack(qb[j]), &out[(size_t)(base + 16 + j) * EE_D4 + lane]);
            // b=2: load batch3 -> qb, store qa (rows 32..47)
            #pragma unroll
            for (int j = 0; j < 16; ++j)
                qb[j] = comb[(size_t)__builtin_amdgcn_readlane(idx, 48 + j) * EE_D4 + lane];
            #pragma unroll
            for (int j = 0; j < 16; ++j)
                __builtin_nontemporal_store(ee_unpack(qa[j]), &out[(size_t)(base + 32 + j) * EE_D4 + lane]);
            // b=3: store qb (rows 48..63)
            #pragma unroll
            for (int j = 0; j < 16; ++j)
                __builtin_nontemporal_store(ee_unpack(qb[j]), &out[(size_t)(base + 48 + j) * EE_D4 + lane]);
        } else {
            for (int j = 0; j < lim; ++j) {
                int t = __shfl(idx, j);
                uvec2 q = comb[(size_t)t * EE_D4 + lane];
                __builtin_nontemporal_store(ee_unpack(q), &out[(size_t)(base + j) * EE_D4 + lane]);
            }
        }
    }
}

extern "C" void kernel_launch(void* const* d_in, const int* in_sizes, int n_in,
                              void* d_out, int out_size, void* d_ws, size_t ws_size,
                              hipStream_t stream) {
    const int*   data          = (const int*)d_in[0];
    const float* attr_table    = (const float*)d_in[1];
    const float* ete           = (const float*)d_in[2];
    const int*   flat_attr_ids = (const int*)d_in[3];
    const int*   attr_seg_ids  = (const int*)d_in[4];
    int N  = in_sizes[0];   // 1,000,000 edges
    int TA = in_sizes[3];   // 50,000 ragged attrs

    // ws layout: comb bf16 (512 KB) | part f32 [SL][1000][64] fvec4 (SL MB)
    char*  ws   = (char*)d_ws;
    uvec2* comb = (uvec2*)ws;
    fvec4* part = (fvec4*)(ws + (512 << 10));
    const size_t partBytes = (size_t)EE_NT * EE_D4 * sizeof(fvec4);   // 1 MB per slice

    if (ws_size >= (512 << 10) + 8 * partBytes) {
        ee_build_part<8><<<dim3(EE_NT / EE_K, 8), 256, 0, stream>>>(
            (const fvec4*)attr_table, flat_attr_ids, attr_seg_ids, part, TA);
        ee_finalize<8><<<EE_NT / EE_K, 256, 0, stream>>>(part, (const fvec4*)ete, comb);
    } else {
        ee_build_part<4><<<dim3(EE_NT / EE_K, 4), 256, 0, stream>>>(
            (const fvec4*)attr_table, flat_attr_ids, attr_seg_ids, part, TA);
        ee_finalize<4><<<EE_NT / EE_K, 256, 0, stream>>>(part, (const fvec4*)ete, comb);
    }

    ee_gather_out<<<2048, 256, 0, stream>>>(
        data, comb, (fvec4*)d_out, N);
}